// Round 11
// baseline (1523.233 us; speedup 1.0000x reference)
//
#include <hip/hip_runtime.h>
#include <hip/hip_bf16.h>

// NeuralODE RK4, bf16 MFMA persistent kernel, swapped-operand layout,
// TWO-TILE INTERLEAVE: 4 waves x 64 cols own TWO 16-row tiles.
// BS=1024, ZDIM=HID=256, TLEN=128 -> 127 steps x 4 stages = 508 phases.
//
// Measured landscape (R1..R10): 8w/16rows = 503us floor; LDS delivery is
// per-wave-read (broadcast doesn't help, R7); fewer reader waves halves
// delivery but single-stream 1-wave/SIMD configs die on exposed latency
// (R6/R8 ~670us); spin-dataflow worse than HW barriers (R10).
// This config: grid 32 WGs x 256 thr (4 waves, 1/SIMD). Each WG: rows
// [32b,32b+16) = tile A, [32b+16,32b+32) = tile B. Per stage, both tiles
// share one barrier pair:
//   delivery: 4 waves x 8 reads x 2 GEMMs x 2 tiles = 128 b128/CU/stage
//             for 32 rows -> per-row HALF of the 503us kernel;
//   barriers: 2 per 32 rows (was 2 per 16);
//   weights:  [4][8] frags (256 VGPR) shared by both tiles (the 2-WG/CU
//             alternative would need them twice -> infeasible).
// The 1-wave/SIMD latency exposure is countered by TWO independent
// dependency streams: A/B reads+MFMAs interleaved at slice level, doubling
// independent work between dependents (what single-stream R8 lacked).
// Full 512-reg budget at 1 wave/SIMD -> no spill (est ~390 live).
//
// Swapped trick: S^T = W^T @ z^T (weights as MFMA A-operand). C/D layout:
// col(lane&15) = batch row m, row(q*4+r) = output col c. Rotated k-slice
// order ks=(2wv+i)&7 with weights PRE-ROTATED at load (static reg indices;
// R4: runtime idx -> scratch, 6.6x).

#define BS   1024
#define ZDIM 256
#define TLEN 128
#define ROWSTRIDE 264   // u16 units; 528 B = 16B-aligned, odd multiple of 4 units

typedef short v8s __attribute__((ext_vector_type(8)));
typedef float v4f __attribute__((ext_vector_type(4)));

static __device__ __forceinline__ ushort f2bf_rne(float x) {
    union { float f; unsigned u; } v; v.f = x;
    unsigned r = v.u + 0x7FFFu + ((v.u >> 16) & 1u);
    return (ushort)(r >> 16);
}

static __device__ __forceinline__ unsigned pk2(float a, float b) {
    union { __hip_bfloat162 h; unsigned u; } cv;
    cv.h = __float22bfloat162_rn(make_float2(a, b));
    return cv.u;
}

static __device__ __forceinline__ float fast_tanh(float x) {
    // tanh(x) = 1 - 2/(exp2(2x*log2e)+1); v_exp + v_rcp, no slow libm div
    float e = __builtin_amdgcn_exp2f(2.88539008177793f * x);
    float r = __builtin_amdgcn_rcpf(e + 1.0f);
    return 1.0f - 2.0f * r;
}

__global__ __launch_bounds__(256, 1)
void ode_mfma_kernel(const float* __restrict__ z0,
                     const float* __restrict__ t,
                     const float* __restrict__ W1,
                     const float* __restrict__ b1,
                     const float* __restrict__ W2,
                     const float* __restrict__ b2,
                     float* __restrict__ out)
{
    // per-tile state buffers, swapped layout [m][c] bf16, row stride ROWSTRIDE
    __shared__ ushort zbA[16 * ROWSTRIDE], zbB[16 * ROWSTRIDE];
    __shared__ ushort hbA[16 * ROWSTRIDE], hbB[16 * ROWSTRIDE];
    __shared__ float  hsh[TLEN];            // per-step h = t[s+1]-t[s]

    const int tid  = threadIdx.x;
    const int wv   = tid >> 6;        // 0..3
    const int lane = tid & 63;
    const int q    = lane >> 4;       // 0..3
    const int ln   = lane & 15;       // = batch row m (within tile)
    const int rowA = blockIdx.x * 32;        // tile A rows
    const int rowB = blockIdx.x * 32 + 16;   // tile B rows

    if (tid < TLEN - 1) hsh[tid] = t[tid + 1] - t[tid];

    // ---- one-time: weights -> registers, A-frag layout, PRE-ROTATED ----
    // wf[ct][i] holds k-slice ks=(2wv+i)&7:
    //   lane has W[k=32ks+8q+j][c = 64wv + 16ct + ln]
    v8s w1f[4][8], w2f[4][8];
    #pragma unroll
    for (int ct = 0; ct < 4; ++ct) {
        const int c = wv * 64 + ct * 16 + ln;
        #pragma unroll
        for (int i = 0; i < 8; ++i) {
            const int ks = (2 * wv + i) & 7;
            v8s a, b;
            #pragma unroll
            for (int j = 0; j < 8; ++j) {
                const int k = ks * 32 + q * 8 + j;
                a[j] = (short)f2bf_rne(W1[k * ZDIM + c]);
                b[j] = (short)f2bf_rne(W2[k * ZDIM + c]);
            }
            w1f[ct][i] = a;
            w2f[ct][i] = b;
        }
    }

    // biases in C'-layout: value row (c = 64wv + 16ct + 4q + r)
    v4f b1f[4], b2f[4];
    #pragma unroll
    for (int ct = 0; ct < 4; ++ct)
        #pragma unroll
        for (int r = 0; r < 4; ++r) {
            b1f[ct][r] = b1[wv * 64 + ct * 16 + q * 4 + r];
            b2f[ct][r] = b2[wv * 64 + ct * 16 + q * 4 + r];
        }

    // LDS offsets (u16 units); rdaddr[i] carries the matching slice rotation
    const int rdbase = ln * ROWSTRIDE + q * 8;            // + 32*ks, b128 reads
    const int wrbase = ln * ROWSTRIDE + wv * 64 + q * 4;  // + 16*ct,  b64 writes
    int rdaddr[8];
    #pragma unroll
    for (int i = 0; i < 8; ++i)
        rdaddr[i] = rdbase + ((2 * wv + i) & 7) * 32;

    // ---- initial state, both tiles ----
    float zlA[4][4], zlB[4][4];   // z[m=ln][c = 64wv+16ct+4q+r], fp32
    #pragma unroll
    for (int ct = 0; ct < 4; ++ct) {
        #pragma unroll
        for (int r = 0; r < 4; ++r) {
            zlA[ct][r] = z0[(rowA + ln) * ZDIM + wv * 64 + ct * 16 + q * 4 + r];
            zlB[ct][r] = z0[(rowB + ln) * ZDIM + wv * 64 + ct * 16 + q * 4 + r];
        }
        uint2 p;
        p.x = pk2(zlA[ct][0], zlA[ct][1]); p.y = pk2(zlA[ct][2], zlA[ct][3]);
        *(uint2*)&zbA[wrbase + ct * 16] = p;
        p.x = pk2(zlB[ct][0], zlB[ct][1]); p.y = pk2(zlB[ct][2], zlB[ct][3]);
        *(uint2*)&zbB[wrbase + ct * 16] = p;
    }
    __syncthreads();

    float kaA[4][4], kaB[4][4];

    #pragma unroll 1
    for (int step = 0; step < TLEN - 1; ++step) {
        const float h = hsh[step];

        #pragma unroll
        for (int stage = 0; stage < 4; ++stage) {
            // ---- GEMM1 both tiles, slice-interleaved (2 indep streams) ----
            v4f aA0 = b1f[0], aA1 = b1f[1], aA2 = b1f[2], aA3 = b1f[3];
            v4f aB0 = b1f[0], aB1 = b1f[1], aB2 = b1f[2], aB3 = b1f[3];
            #pragma unroll
            for (int i = 0; i < 8; ++i) {
                const v8s zfA = *(const v8s*)&zbA[rdaddr[i]];
                const v8s zfB = *(const v8s*)&zbB[rdaddr[i]];
                aA0 = __builtin_amdgcn_mfma_f32_16x16x32_bf16(w1f[0][i], zfA, aA0, 0, 0, 0);
                aB0 = __builtin_amdgcn_mfma_f32_16x16x32_bf16(w1f[0][i], zfB, aB0, 0, 0, 0);
                aA1 = __builtin_amdgcn_mfma_f32_16x16x32_bf16(w1f[1][i], zfA, aA1, 0, 0, 0);
                aB1 = __builtin_amdgcn_mfma_f32_16x16x32_bf16(w1f[1][i], zfB, aB1, 0, 0, 0);
                aA2 = __builtin_amdgcn_mfma_f32_16x16x32_bf16(w1f[2][i], zfA, aA2, 0, 0, 0);
                aB2 = __builtin_amdgcn_mfma_f32_16x16x32_bf16(w1f[2][i], zfB, aB2, 0, 0, 0);
                aA3 = __builtin_amdgcn_mfma_f32_16x16x32_bf16(w1f[3][i], zfA, aA3, 0, 0, 0);
                aB3 = __builtin_amdgcn_mfma_f32_16x16x32_bf16(w1f[3][i], zfB, aB3, 0, 0, 0);
            }
            // tanh -> hbufs; write each uint2 as soon as it's packed
            {
                uint2 p;
                p.x = pk2(fast_tanh(aA0[0]), fast_tanh(aA0[1]));
                p.y = pk2(fast_tanh(aA0[2]), fast_tanh(aA0[3]));
                *(uint2*)&hbA[wrbase] = p;
                p.x = pk2(fast_tanh(aB0[0]), fast_tanh(aB0[1]));
                p.y = pk2(fast_tanh(aB0[2]), fast_tanh(aB0[3]));
                *(uint2*)&hbB[wrbase] = p;
                p.x = pk2(fast_tanh(aA1[0]), fast_tanh(aA1[1]));
                p.y = pk2(fast_tanh(aA1[2]), fast_tanh(aA1[3]));
                *(uint2*)&hbA[wrbase + 16] = p;
                p.x = pk2(fast_tanh(aB1[0]), fast_tanh(aB1[1]));
                p.y = pk2(fast_tanh(aB1[2]), fast_tanh(aB1[3]));
                *(uint2*)&hbB[wrbase + 16] = p;
                p.x = pk2(fast_tanh(aA2[0]), fast_tanh(aA2[1]));
                p.y = pk2(fast_tanh(aA2[2]), fast_tanh(aA2[3]));
                *(uint2*)&hbA[wrbase + 32] = p;
                p.x = pk2(fast_tanh(aB2[0]), fast_tanh(aB2[1]));
                p.y = pk2(fast_tanh(aB2[2]), fast_tanh(aB2[3]));
                *(uint2*)&hbB[wrbase + 32] = p;
                p.x = pk2(fast_tanh(aA3[0]), fast_tanh(aA3[1]));
                p.y = pk2(fast_tanh(aA3[2]), fast_tanh(aA3[3]));
                *(uint2*)&hbA[wrbase + 48] = p;
                p.x = pk2(fast_tanh(aB3[0]), fast_tanh(aB3[1]));
                p.y = pk2(fast_tanh(aB3[2]), fast_tanh(aB3[3]));
                *(uint2*)&hbB[wrbase + 48] = p;
            }
            __syncthreads();

            // ---- GEMM2 both tiles, slice-interleaved ----
            v4f fA0 = b2f[0], fA1 = b2f[1], fA2 = b2f[2], fA3 = b2f[3];
            v4f fB0 = b2f[0], fB1 = b2f[1], fB2 = b2f[2], fB3 = b2f[3];
            #pragma unroll
            for (int i = 0; i < 8; ++i) {
                const v8s hfA = *(const v8s*)&hbA[rdaddr[i]];
                const v8s hfB = *(const v8s*)&hbB[rdaddr[i]];
                fA0 = __builtin_amdgcn_mfma_f32_16x16x32_bf16(w2f[0][i], hfA, fA0, 0, 0, 0);
                fB0 = __builtin_amdgcn_mfma_f32_16x16x32_bf16(w2f[0][i], hfB, fB0, 0, 0, 0);
                fA1 = __builtin_amdgcn_mfma_f32_16x16x32_bf16(w2f[1][i], hfA, fA1, 0, 0, 0);
                fB1 = __builtin_amdgcn_mfma_f32_16x16x32_bf16(w2f[1][i], hfB, fB1, 0, 0, 0);
                fA2 = __builtin_amdgcn_mfma_f32_16x16x32_bf16(w2f[2][i], hfA, fA2, 0, 0, 0);
                fB2 = __builtin_amdgcn_mfma_f32_16x16x32_bf16(w2f[2][i], hfB, fB2, 0, 0, 0);
                fA3 = __builtin_amdgcn_mfma_f32_16x16x32_bf16(w2f[3][i], hfA, fA3, 0, 0, 0);
                fB3 = __builtin_amdgcn_mfma_f32_16x16x32_bf16(w2f[3][i], hfB, fB3, 0, 0, 0);
            }
            v4f faA[4] = { fA0, fA1, fA2, fA3 };
            v4f faB[4] = { fB0, fB1, fB2, fB3 };

            // ---- RK4 epilogue: zn pack+write both tiles before the barrier ----
            if (stage < 3) {
                const float c = (stage == 2) ? h : 0.5f * h;
                #pragma unroll
                for (int ct = 0; ct < 4; ++ct) {
                    float zn[4];
                    #pragma unroll
                    for (int r = 0; r < 4; ++r) zn[r] = zlA[ct][r] + c * faA[ct][r];
                    uint2 p; p.x = pk2(zn[0], zn[1]); p.y = pk2(zn[2], zn[3]);
                    *(uint2*)&zbA[wrbase + ct * 16] = p;
                    #pragma unroll
                    for (int r = 0; r < 4; ++r) zn[r] = zlB[ct][r] + c * faB[ct][r];
                    p.x = pk2(zn[0], zn[1]); p.y = pk2(zn[2], zn[3]);
                    *(uint2*)&zbB[wrbase + ct * 16] = p;
                }
                __syncthreads();
                // deferred kacc bookkeeping: overlaps next GEMM1's reads
                #pragma unroll
                for (int ct = 0; ct < 4; ++ct)
                    #pragma unroll
                    for (int r = 0; r < 4; ++r) {
                        if (stage == 0) { kaA[ct][r] = faA[ct][r]; kaB[ct][r] = faB[ct][r]; }
                        else { kaA[ct][r] += 2.0f * faA[ct][r]; kaB[ct][r] += 2.0f * faB[ct][r]; }
                    }
            } else {
                #pragma unroll
                for (int ct = 0; ct < 4; ++ct) {
                    #pragma unroll
                    for (int r = 0; r < 4; ++r) {
                        kaA[ct][r] += faA[ct][r];
                        zlA[ct][r] += (h * (1.0f / 6.0f)) * kaA[ct][r];
                        kaB[ct][r] += faB[ct][r];
                        zlB[ct][r] += (h * (1.0f / 6.0f)) * kaB[ct][r];
                    }
                    uint2 p;
                    p.x = pk2(zlA[ct][0], zlA[ct][1]); p.y = pk2(zlA[ct][2], zlA[ct][3]);
                    *(uint2*)&zbA[wrbase + ct * 16] = p;
                    p.x = pk2(zlB[ct][0], zlB[ct][1]); p.y = pk2(zlB[ct][2], zlB[ct][3]);
                    *(uint2*)&zbB[wrbase + ct * 16] = p;
                }
                __syncthreads();
            }
        }
    }

    // ---- final store, both tiles (one-time, uncoalesced is fine) ----
    #pragma unroll
    for (int ct = 0; ct < 4; ++ct)
        #pragma unroll
        for (int r = 0; r < 4; ++r) {
            out[(rowA + ln) * ZDIM + wv * 64 + ct * 16 + q * 4 + r] = zlA[ct][r];
            out[(rowB + ln) * ZDIM + wv * 64 + ct * 16 + q * 4 + r] = zlB[ct][r];
        }
}

extern "C" void kernel_launch(void* const* d_in, const int* in_sizes, int n_in,
                              void* d_out, int out_size, void* d_ws, size_t ws_size,
                              hipStream_t stream) {
    const float* z0 = (const float*)d_in[0];
    const float* t  = (const float*)d_in[1];
    const float* W1 = (const float*)d_in[2];
    const float* b1 = (const float*)d_in[3];
    const float* W2 = (const float*)d_in[4];
    const float* b2 = (const float*)d_in[5];
    float* out = (float*)d_out;

    dim3 grid(BS / 32);    // 32 workgroups, 32 batch rows each (2 tiles)
    dim3 block(256);       // 4 waves, 1 per SIMD, 64 cols each
    hipLaunchKernelGGL(ode_mfma_kernel, grid, block, 0, stream,
                       z0, t, W1, b1, W2, b2, out);
}

// Round 12
// 559.269 us; speedup vs baseline: 2.7236x; 2.7236x over previous
//
#include <hip/hip_runtime.h>
#include <hip/hip_bf16.h>

// NeuralODE RK4, bf16 MFMA persistent kernel, swapped-operand layout,
// OWN-SLICE PEELING (pre-barrier read of the slice this wave just wrote).
// BS=1024, ZDIM=HID=256, TLEN=128 -> 127 steps x 4 stages = 508 f-evals.
//
// Structure locked by measurement (R1-R11): 8 waves x 16 rows x 2/SIMD.
// Every deviation lost >=30%: role-split(R1), 4-wave(R6/R8), 8-row(R7),
// spin-dataflow(R10), two-tile 4-wave(R11, spill). Stage ledger at 503us:
// delivery 128xb128 ~1536cy (structural), MFMA ~260, tails ~400,
// post-barrier ramp ~120x2 <- THIS revision's target.
//
// Own-slice peel: with rotated order ks=(wv+i)&7, slice i=0 is the wave's
// OWN output (wave wv writes exactly cols [32wv,32wv+32) = k-slice wv).
// Read it BEFORE the barrier: race-free (other waves write disjoint slices;
// cross-wave readers of old data are behind the previous barrier; an
// explicit lgkmcnt(0) fence orders the wave's own writes before the read).
// The peeled read completes during the barrier wait -> first MFMAs issue
// with zero post-barrier latency, covering the remaining 7 reads' ramp.
//
// Swapped trick: S^T = W^T @ z^T (weights as MFMA A-operand). C/D layout:
// col(lane&15) = batch row m, row(q*4+r) = output col c. LDS round-trip is
// per-m contiguous: packed b64 writes, b128 frag reads, row stride 264 u16.
// Weight frags PRE-ROTATED at load (static reg indices; R4: runtime idx ->
// scratch, 6.6x).

#define BS   1024
#define ZDIM 256
#define TLEN 128
#define ROWSTRIDE 264   // u16 units; 528 B = 16B-aligned, odd multiple of 4 units

typedef short v8s __attribute__((ext_vector_type(8)));
typedef float v4f __attribute__((ext_vector_type(4)));

static __device__ __forceinline__ ushort f2bf_rne(float x) {
    union { float f; unsigned u; } v; v.f = x;
    unsigned r = v.u + 0x7FFFu + ((v.u >> 16) & 1u);
    return (ushort)(r >> 16);
}

static __device__ __forceinline__ unsigned pk2(float a, float b) {
    union { __hip_bfloat162 h; unsigned u; } cv;
    cv.h = __float22bfloat162_rn(make_float2(a, b));
    return cv.u;
}

static __device__ __forceinline__ float fast_tanh(float x) {
    // tanh(x) = 1 - 2/(exp2(2x*log2e)+1); v_exp + v_rcp, no slow libm div
    float e = __builtin_amdgcn_exp2f(2.88539008177793f * x);
    float r = __builtin_amdgcn_rcpf(e + 1.0f);
    return 1.0f - 2.0f * r;
}

// order own ds_writes before the peeled own-slice read
#define LDS_FENCE() asm volatile("s_waitcnt lgkmcnt(0)" ::: "memory")

__global__ __launch_bounds__(512, 2)
void ode_mfma_kernel(const float* __restrict__ z0,
                     const float* __restrict__ t,
                     const float* __restrict__ W1,
                     const float* __restrict__ b1,
                     const float* __restrict__ W2,
                     const float* __restrict__ b2,
                     float* __restrict__ out)
{
    // state buffers, swapped layout: buf[m][c] bf16, row stride ROWSTRIDE
    __shared__ ushort zbuf[16 * ROWSTRIDE];
    __shared__ ushort hbuf[16 * ROWSTRIDE];
    __shared__ float  hsh[TLEN];            // per-step h = t[s+1]-t[s]

    const int tid  = threadIdx.x;
    const int wv   = tid >> 6;        // 0..7
    const int lane = tid & 63;
    const int q    = lane >> 4;       // 0..3
    const int ln   = lane & 15;       // = batch row m (within tile)
    const int rowbase = blockIdx.x * 16;

    if (tid < TLEN - 1) hsh[tid] = t[tid + 1] - t[tid];

    // ---- one-time: weights -> registers, A-frag layout, PRE-ROTATED ----
    // wf[ct][i] holds k-slice ks=(wv+i)&7: lane has W[k=32ks+8q+j][c=32wv+16ct+ln]
    v8s w1f[2][8], w2f[2][8];
    #pragma unroll
    for (int ct = 0; ct < 2; ++ct) {
        const int c = wv * 32 + ct * 16 + ln;
        #pragma unroll
        for (int i = 0; i < 8; ++i) {
            const int ks = (wv + i) & 7;
            v8s a, b;
            #pragma unroll
            for (int j = 0; j < 8; ++j) {
                const int k = ks * 32 + q * 8 + j;
                a[j] = (short)f2bf_rne(W1[k * ZDIM + c]);
                b[j] = (short)f2bf_rne(W2[k * ZDIM + c]);
            }
            w1f[ct][i] = a;
            w2f[ct][i] = b;
        }
    }

    // biases in C'-layout: value row (c = 32wv + 16ct + 4q + r)
    v4f b1f[2], b2f[2];
    #pragma unroll
    for (int ct = 0; ct < 2; ++ct)
        #pragma unroll
        for (int r = 0; r < 4; ++r) {
            b1f[ct][r] = b1[wv * 32 + ct * 16 + q * 4 + r];
            b2f[ct][r] = b2[wv * 32 + ct * 16 + q * 4 + r];
        }

    // LDS offsets (u16 units); rdaddr[i] carries the matching slice rotation
    const int rdbase = ln * ROWSTRIDE + q * 8;            // + 32*ks, b128 reads
    const int wrbase = ln * ROWSTRIDE + wv * 32 + q * 4;  // + 16*ct,  b64 writes
    int rdaddr[8];
    #pragma unroll
    for (int i = 0; i < 8; ++i)
        rdaddr[i] = rdbase + ((wv + i) & 7) * 32;

    // ---- initial state ----
    float zloc[2][4];   // z[m=ln][c = 32wv+16ct+4q+r], fp32
    #pragma unroll
    for (int ct = 0; ct < 2; ++ct) {
        #pragma unroll
        for (int r = 0; r < 4; ++r)
            zloc[ct][r] = z0[(rowbase + ln) * ZDIM + wv * 32 + ct * 16 + q * 4 + r];
        uint2 p; p.x = pk2(zloc[ct][0], zloc[ct][1]); p.y = pk2(zloc[ct][2], zloc[ct][3]);
        *(uint2*)&zbuf[wrbase + ct * 16] = p;
    }
    // peel own z-slice (slice wv = this wave's just-written cols)
    LDS_FENCE();
    v8s zf0 = *(const v8s*)&zbuf[rdaddr[0]];
    __syncthreads();

    float kacc[2][4];

    #pragma unroll 1
    for (int step = 0; step < TLEN - 1; ++step) {
        const float h = hsh[step];

        #pragma unroll
        for (int stage = 0; stage < 4; ++stage) {
            // ---- GEMM1: S^T = W1^T z^T + b1 (slice 0 pre-peeled) ----
            v4f acc0 = b1f[0], acc1 = b1f[1];
            acc0 = __builtin_amdgcn_mfma_f32_16x16x32_bf16(w1f[0][0], zf0, acc0, 0, 0, 0);
            acc1 = __builtin_amdgcn_mfma_f32_16x16x32_bf16(w1f[1][0], zf0, acc1, 0, 0, 0);
            #pragma unroll
            for (int i = 1; i < 8; ++i) {
                const v8s zf = *(const v8s*)&zbuf[rdaddr[i]];
                acc0 = __builtin_amdgcn_mfma_f32_16x16x32_bf16(w1f[0][i], zf, acc0, 0, 0, 0);
                acc1 = __builtin_amdgcn_mfma_f32_16x16x32_bf16(w1f[1][i], zf, acc1, 0, 0, 0);
            }
            // tanh -> hbuf; write p0 before computing p1; peel own h-slice
            v8s hf0;
            {
                uint2 p0;
                p0.x = pk2(fast_tanh(acc0[0]), fast_tanh(acc0[1]));
                p0.y = pk2(fast_tanh(acc0[2]), fast_tanh(acc0[3]));
                *(uint2*)&hbuf[wrbase] = p0;
                uint2 p1;
                p1.x = pk2(fast_tanh(acc1[0]), fast_tanh(acc1[1]));
                p1.y = pk2(fast_tanh(acc1[2]), fast_tanh(acc1[3]));
                *(uint2*)&hbuf[wrbase + 16] = p1;
                LDS_FENCE();
                hf0 = *(const v8s*)&hbuf[rdaddr[0]];
            }
            __syncthreads();

            // ---- GEMM2: f^T = W2^T h^T + b2 (slice 0 pre-peeled) ----
            v4f fv0 = b2f[0], fv1 = b2f[1];
            fv0 = __builtin_amdgcn_mfma_f32_16x16x32_bf16(w2f[0][0], hf0, fv0, 0, 0, 0);
            fv1 = __builtin_amdgcn_mfma_f32_16x16x32_bf16(w2f[1][0], hf0, fv1, 0, 0, 0);
            #pragma unroll
            for (int i = 1; i < 8; ++i) {
                const v8s hf = *(const v8s*)&hbuf[rdaddr[i]];
                fv0 = __builtin_amdgcn_mfma_f32_16x16x32_bf16(w2f[0][i], hf, fv0, 0, 0, 0);
                fv1 = __builtin_amdgcn_mfma_f32_16x16x32_bf16(w2f[1][i], hf, fv1, 0, 0, 0);
            }

            // ---- RK4 epilogue: zn pack+write, peel own z-slice, barrier ----
            if (stage < 3) {
                const float c = (stage == 2) ? h : 0.5f * h;
                #pragma unroll
                for (int ct = 0; ct < 2; ++ct) {
                    const v4f f = ct ? fv1 : fv0;
                    float zn[4];
                    #pragma unroll
                    for (int r = 0; r < 4; ++r) zn[r] = zloc[ct][r] + c * f[r];
                    uint2 p; p.x = pk2(zn[0], zn[1]); p.y = pk2(zn[2], zn[3]);
                    *(uint2*)&zbuf[wrbase + ct * 16] = p;
                }
                LDS_FENCE();
                zf0 = *(const v8s*)&zbuf[rdaddr[0]];
                __syncthreads();
                // deferred kacc bookkeeping: overlaps next GEMM1's reads
                #pragma unroll
                for (int ct = 0; ct < 2; ++ct) {
                    const v4f f = ct ? fv1 : fv0;
                    #pragma unroll
                    for (int r = 0; r < 4; ++r) {
                        if (stage == 0) kacc[ct][r] = f[r];
                        else            kacc[ct][r] += 2.0f * f[r];
                    }
                }
            } else {
                #pragma unroll
                for (int ct = 0; ct < 2; ++ct) {
                    const v4f f = ct ? fv1 : fv0;
                    #pragma unroll
                    for (int r = 0; r < 4; ++r) {
                        kacc[ct][r] += f[r];
                        zloc[ct][r] += (h * (1.0f / 6.0f)) * kacc[ct][r];
                    }
                    uint2 p; p.x = pk2(zloc[ct][0], zloc[ct][1]);
                    p.y = pk2(zloc[ct][2], zloc[ct][3]);
                    *(uint2*)&zbuf[wrbase + ct * 16] = p;
                }
                LDS_FENCE();
                zf0 = *(const v8s*)&zbuf[rdaddr[0]];
                __syncthreads();
            }
        }
    }

    // ---- final store (one-time, uncoalesced is fine) ----
    #pragma unroll
    for (int ct = 0; ct < 2; ++ct)
        #pragma unroll
        for (int r = 0; r < 4; ++r)
            out[(rowbase + ln) * ZDIM + wv * 32 + ct * 16 + q * 4 + r] = zloc[ct][r];
}

extern "C" void kernel_launch(void* const* d_in, const int* in_sizes, int n_in,
                              void* d_out, int out_size, void* d_ws, size_t ws_size,
                              hipStream_t stream) {
    const float* z0 = (const float*)d_in[0];
    const float* t  = (const float*)d_in[1];
    const float* W1 = (const float*)d_in[2];
    const float* b1 = (const float*)d_in[3];
    const float* W2 = (const float*)d_in[4];
    const float* b2 = (const float*)d_in[5];
    float* out = (float*)d_out;

    dim3 grid(BS / 16);    // 64 workgroups, 16 batch rows each
    dim3 block(512);       // 8 waves, 2 per SIMD
    hipLaunchKernelGGL(ode_mfma_kernel, grid, block, 0, stream,
                       z0, t, W1, b1, W2, b2, out);
}